// Round 4
// baseline (152.715 us; speedup 1.0000x reference)
//
#include <hip/hip_runtime.h>

#define NE 8
#define HD 128
#define NPTS 65536
#define TM 64   // points per block

typedef __bf16 bf16x8 __attribute__((ext_vector_type(8)));
typedef __bf16 bf16x4 __attribute__((ext_vector_type(4)));
typedef float f32x4 __attribute__((ext_vector_type(4)));

__device__ __forceinline__ unsigned int f2bf(float f) {
    unsigned int u = __float_as_uint(f);
    u += 0x7FFFu + ((u >> 16) & 1u);   // RNE
    return u >> 16;
}

// XOR swizzle on 256B rows: spreads 8 consecutive rows across 8 distinct 16B slots
__device__ __forceinline__ unsigned int swz(int row, int byte_in_row) {
    return (unsigned int)((row * 256 + byte_in_row) ^ ((row & 7) << 4));
}

// LDS-only barrier: drains ds ops but leaves global (vmcnt) loads in flight.
__device__ __forceinline__ void bar_lds() {
    asm volatile("s_waitcnt lgkmcnt(0)\ns_barrier" ::: "memory");
}

// Weight A-fragments from global/L2: a[ca][kb], c = tc + ca*16 + lr, k = kb*32 + lg*8
template<int KB0, int KB1>
__device__ __forceinline__ void loadW(const unsigned short* __restrict__ Ag,
                                      bf16x8 (&a)[4][4], int tc, int lr, int lg) {
#pragma unroll
    for (int ca = 0; ca < 4; ++ca)
#pragma unroll
        for (int kb = KB0; kb < KB1; ++kb)
            a[ca][kb] = *(const bf16x8*)(Ag + (tc + ca * 16 + lr) * HD + kb * 32 + lg * 8);
}

__device__ __forceinline__ void loadW0(const unsigned short* __restrict__ Ag,
                                       bf16x8 (&a0)[4], int tc, int lr, int lg) {
#pragma unroll
    for (int ca = 0; ca < 4; ++ca)
        a0[ca] = *(const bf16x8*)(Ag + (tc + ca * 16 + lr) * 32 + lg * 8);
}

// bias + relu + bf16-pack + swizzled LDS store; 64 cols x 32 points per wave
__device__ __forceinline__ void epi_store(const f32x4 (&acc)[4][2], char* Db,
                                          const float* __restrict__ bias,
                                          int tc, int pr0, int lr, int lg) {
#pragma unroll
    for (int ca = 0; ca < 4; ++ca) {
        int c0 = tc + ca * 16 + lg * 4;
        float4 bs = *(const float4*)(bias + c0);
#pragma unroll
        for (int nb = 0; nb < 2; ++nb) {
            int r = pr0 + nb * 16 + lr;
            bf16x4 pk;
            pk[0] = (__bf16)fmaxf(acc[ca][nb][0] + bs.x, 0.f);
            pk[1] = (__bf16)fmaxf(acc[ca][nb][1] + bs.y, 0.f);
            pk[2] = (__bf16)fmaxf(acc[ca][nb][2] + bs.z, 0.f);
            pk[3] = (__bf16)fmaxf(acc[ca][nb][3] + bs.w, 0.f);
            *(bf16x4*)(Db + swz(r, c0 * 2)) = pk;
        }
    }
}

// Prep: fp32 -> bf16 weights. W0 padded K:3->32 with zeros.
__global__ void prep_kernel(const float* __restrict__ W0,
                            const float* __restrict__ W1,
                            const float* __restrict__ W2,
                            unsigned int* __restrict__ W1b,
                            unsigned int* __restrict__ W2b,
                            unsigned int* __restrict__ W0p) {
    int i = blockIdx.x * 256 + threadIdx.x;  // 0..65535
    float2 v = *(const float2*)(W1 + 2 * i);
    W1b[i] = f2bf(v.x) | (f2bf(v.y) << 16);
    float2 u = *(const float2*)(W2 + 2 * i);
    W2b[i] = f2bf(u.x) | (f2bf(u.y) << 16);
    if (i < NE * HD * 16) {
        int row = i >> 4;
        int kk = (i & 15) * 2;
        float a = (kk < 3) ? W0[row * 3 + kk] : 0.f;
        float b = (kk + 1 < 3) ? W0[row * 3 + kk + 1] : 0.f;
        W0p[i] = f2bf(a) | (f2bf(b) << 16);
    }
}

__global__ __launch_bounds__(256, 4) void moe_main(
    const float* __restrict__ coords,
    const float* __restrict__ b0, const float* __restrict__ b1,
    const float* __restrict__ b2,
    const float* __restrict__ Wo, const float* __restrict__ bo,
    const unsigned short* __restrict__ W0p,
    const unsigned short* __restrict__ W1b,
    const unsigned short* __restrict__ W2b,
    float* __restrict__ out) {
    __shared__ __align__(16) unsigned short hA[TM * HD];   // 16 KB, swizzled 256B rows
    __shared__ __align__(16) unsigned short hB[TM * HD];   // 16 KB
    __shared__ __align__(16) unsigned short Xp[TM * 40];   // 5 KB, 80B rows: conflict-free
    __shared__ __align__(16) float part[128];              // [col-half][point]

    const int tid = threadIdx.x;
    const int lane = tid & 63;
    const int w = tid >> 6;
    const int lr = lane & 15;
    const int lg = lane >> 4;
    const int ch = w & 1;        // col half
    const int pc = w >> 1;       // point half
    const int tc = ch * 64;
    const int pr0 = pc * 32;
    const int row0 = blockIdx.x * TM;

    for (int i = tid; i < TM * 40; i += 256) Xp[i] = 0;
    __syncthreads();
    if (tid < TM * 3) {
        int r = tid / 3, k = tid % 3;
        Xp[r * 40 + k] = (unsigned short)f2bf(coords[row0 * 3 + tid]);
    }
    __syncthreads();

    float bmax = -3.0e38f;
    bf16x8 a0[4], a1[4][4], a2[4][4];
    loadW0(W0p, a0, tc, lr, lg);
    loadW<0, 2>(W1b, a1, tc, lr, lg);

    for (int e = 0; e < NE; ++e) {
        const unsigned short* W1e = W1b + e * HD * HD;
        const unsigned short* W2e = W2b + e * HD * HD;
        const int e1 = (e < NE - 1) ? e + 1 : e;
        f32x4 acc[4][2];

        // ---- layer 0: h1 = relu(X*W0^T + b0) -> hA ----
#pragma unroll
        for (int ca = 0; ca < 4; ++ca)
#pragma unroll
            for (int nb = 0; nb < 2; ++nb) acc[ca][nb] = (f32x4){0.f, 0.f, 0.f, 0.f};
        {
            bf16x8 b[2];
#pragma unroll
            for (int nb = 0; nb < 2; ++nb)
                b[nb] = *(const bf16x8*)(Xp + (pr0 + nb * 16 + lr) * 40 + lg * 8);
#pragma unroll
            for (int ca = 0; ca < 4; ++ca)
#pragma unroll
                for (int nb = 0; nb < 2; ++nb)
                    acc[ca][nb] = __builtin_amdgcn_mfma_f32_16x16x32_bf16(a0[ca], b[nb], acc[ca][nb], 0, 0, 0);
        }
        loadW<2, 4>(W1e, a1, tc, lr, lg);   // second half of W1 frags, in flight across bar
        epi_store(acc, (char*)hA, b0 + e * HD, tc, pr0, lr, lg);
        bar_lds();

        // ---- layer 1: h2 = relu(h1*W1^T + b1) -> hB ----
#pragma unroll
        for (int ca = 0; ca < 4; ++ca)
#pragma unroll
            for (int nb = 0; nb < 2; ++nb) acc[ca][nb] = (f32x4){0.f, 0.f, 0.f, 0.f};
#pragma unroll
        for (int kb = 0; kb < 4; ++kb) {
            bf16x8 b[2];
#pragma unroll
            for (int nb = 0; nb < 2; ++nb)
                b[nb] = *(const bf16x8*)(((const char*)hA) + swz(pr0 + nb * 16 + lr, kb * 64 + lg * 16));
#pragma unroll
            for (int ca = 0; ca < 4; ++ca)
#pragma unroll
                for (int nb = 0; nb < 2; ++nb)
                    acc[ca][nb] = __builtin_amdgcn_mfma_f32_16x16x32_bf16(a1[ca][kb], b[nb], acc[ca][nb], 0, 0, 0);
        }
        loadW<0, 2>(W2e, a2, tc, lr, lg);   // first half of W2 frags
        epi_store(acc, (char*)hB, b1 + e * HD, tc, pr0, lr, lg);
        bar_lds();

        // ---- layer 2 + fused output dot ----
        loadW<2, 4>(W2e, a2, tc, lr, lg);
#pragma unroll
        for (int ca = 0; ca < 4; ++ca)
#pragma unroll
            for (int nb = 0; nb < 2; ++nb) acc[ca][nb] = (f32x4){0.f, 0.f, 0.f, 0.f};
#pragma unroll
        for (int kb = 0; kb < 4; ++kb) {
            bf16x8 b[2];
#pragma unroll
            for (int nb = 0; nb < 2; ++nb)
                b[nb] = *(const bf16x8*)(((const char*)hB) + swz(pr0 + nb * 16 + lr, kb * 64 + lg * 16));
#pragma unroll
            for (int ca = 0; ca < 4; ++ca)
#pragma unroll
                for (int nb = 0; nb < 2; ++nb)
                    acc[ca][nb] = __builtin_amdgcn_mfma_f32_16x16x32_bf16(a2[ca][kb], b[nb], acc[ca][nb], 0, 0, 0);
        }
        loadW0(W0p + e1 * HD * 32, a0, tc, lr, lg);   // next expert prefetch
        loadW<0, 2>(W1b + e1 * HD * HD, a1, tc, lr, lg);

        {
            const float* b2e = b2 + e * HD;
            const float* Woe = Wo + e * HD;
            float s[2] = {0.f, 0.f};
#pragma unroll
            for (int ca = 0; ca < 4; ++ca) {
                int c0 = tc + ca * 16 + lg * 4;
                float4 bs = *(const float4*)(b2e + c0);
                float4 wo = *(const float4*)(Woe + c0);
#pragma unroll
                for (int nb = 0; nb < 2; ++nb) {
                    float v0 = fmaxf(acc[ca][nb][0] + bs.x, 0.f);
                    float v1 = fmaxf(acc[ca][nb][1] + bs.y, 0.f);
                    float v2 = fmaxf(acc[ca][nb][2] + bs.z, 0.f);
                    float v3 = fmaxf(acc[ca][nb][3] + bs.w, 0.f);
                    s[nb] += v0 * wo.x + v1 * wo.y + v2 * wo.z + v3 * wo.w;
                }
            }
#pragma unroll
            for (int nb = 0; nb < 2; ++nb) {
                s[nb] += __shfl_xor(s[nb], 16);
                s[nb] += __shfl_xor(s[nb], 32);
            }
            if (lg == 0) {
#pragma unroll
                for (int nb = 0; nb < 2; ++nb) part[ch * 64 + pr0 + nb * 16 + lr] = s[nb];
            }
        }
        bar_lds();

        if (tid < TM) bmax = fmaxf(bmax, part[tid] + part[64 + tid] + bo[e]);
    }

    if (tid < TM) out[row0 + tid] = bmax;
}

extern "C" void kernel_launch(void* const* d_in, const int* in_sizes, int n_in,
                              void* d_out, int out_size, void* d_ws, size_t ws_size,
                              hipStream_t stream) {
    const float* coords = (const float*)d_in[0];
    const float* W0 = (const float*)d_in[1];
    const float* b0 = (const float*)d_in[2];
    const float* W1 = (const float*)d_in[3];
    const float* b1 = (const float*)d_in[4];
    const float* W2 = (const float*)d_in[5];
    const float* b2 = (const float*)d_in[6];
    const float* Wo = (const float*)d_in[7];
    const float* bo = (const float*)d_in[8];
    float* out = (float*)d_out;

    char* ws = (char*)d_ws;
    unsigned short* W1b = (unsigned short*)(ws);            // 256 KB
    unsigned short* W2b = (unsigned short*)(ws + 262144);   // 256 KB
    unsigned short* W0p = (unsigned short*)(ws + 524288);   // 64 KB

    prep_kernel<<<dim3(256), dim3(256), 0, stream>>>(
        W0, W1, W2, (unsigned int*)W1b, (unsigned int*)W2b, (unsigned int*)W0p);

    moe_main<<<dim3(NPTS / TM), dim3(256), 0, stream>>>(
        coords, b0, b1, b2, Wo, bo, W0p, W1b, W2b, out);
}

// Round 5
// 83.944 us; speedup vs baseline: 1.8193x; 1.8193x over previous
//
#include <hip/hip_runtime.h>

#define NE 8
#define HD 128
#define NPTS 65536
#define TM 64   // points per block

typedef __bf16 bf16x8 __attribute__((ext_vector_type(8)));
typedef __bf16 bf16x4 __attribute__((ext_vector_type(4)));
typedef float f32x4 __attribute__((ext_vector_type(4)));

__device__ __forceinline__ unsigned int f2bf(float f) {
    unsigned int u = __float_as_uint(f);
    u += 0x7FFFu + ((u >> 16) & 1u);   // RNE
    return u >> 16;
}

// XOR swizzle on 256B rows: spreads 8 consecutive rows across 8 distinct 16B slots
__device__ __forceinline__ unsigned int swz(int row, int byte_in_row) {
    return (unsigned int)((row * 256 + byte_in_row) ^ ((row & 7) << 4));
}

// LDS-only barrier: drains ds ops but leaves global (vmcnt) loads in flight.
__device__ __forceinline__ void bar_lds() {
    asm volatile("s_waitcnt lgkmcnt(0)\ns_barrier" ::: "memory");
}

// Weight A-fragments from global/L2: a[ca][kb], c = tc + ca*16 + lr, k = kb*32 + lg*8
template<int KB0, int KB1>
__device__ __forceinline__ void loadA128(const unsigned short* __restrict__ Ag,
                                         bf16x8 (&a)[2][4], int tc, int lr, int lg) {
#pragma unroll
    for (int ca = 0; ca < 2; ++ca)
#pragma unroll
        for (int kb = KB0; kb < KB1; ++kb)
            a[ca][kb] = *(const bf16x8*)(Ag + (tc + ca * 16 + lr) * HD + kb * 32 + lg * 8);
}

__device__ __forceinline__ void loadA32(const unsigned short* __restrict__ Ag,
                                        bf16x8 (&a)[2][1], int tc, int lr, int lg) {
#pragma unroll
    for (int ca = 0; ca < 2; ++ca)
        a[ca][0] = *(const bf16x8*)(Ag + (tc + ca * 16 + lr) * 32 + lg * 8);
}

// MFMA core: acc[ca][nb] += B(points) x A(weights) over NKB k-blocks
template<int NKB, bool BSWZ, int BSTR>
__device__ __forceinline__ void gemm_core(const bf16x8 (&a)[2][NKB], const char* Bb,
                                          f32x4 (&acc)[2][4], int lr, int lg) {
#pragma unroll
    for (int kb = 0; kb < NKB; ++kb) {
        bf16x8 b[4];
#pragma unroll
        for (int nb = 0; nb < 4; ++nb) {
            int r = nb * 16 + lr;
            int byte = kb * 64 + lg * 16;
            const char* p = BSWZ ? (Bb + swz(r, byte)) : (Bb + r * BSTR + byte);
            b[nb] = *(const bf16x8*)p;
        }
#pragma unroll
        for (int ca = 0; ca < 2; ++ca)
#pragma unroll
            for (int nb = 0; nb < 4; ++nb)
                acc[ca][nb] = __builtin_amdgcn_mfma_f32_16x16x32_bf16(a[ca][kb], b[nb], acc[ca][nb], 0, 0, 0);
    }
}

// bias + relu + bf16-pack + swizzled LDS store
__device__ __forceinline__ void epi_store(const f32x4 (&acc)[2][4], char* Db,
                                          const float* __restrict__ bias,
                                          int tc, int lr, int lg) {
#pragma unroll
    for (int ca = 0; ca < 2; ++ca) {
        int c0 = tc + ca * 16 + lg * 4;
        float4 bs = *(const float4*)(bias + c0);
#pragma unroll
        for (int nb = 0; nb < 4; ++nb) {
            int r = nb * 16 + lr;
            bf16x4 pk;
            pk[0] = (__bf16)fmaxf(acc[ca][nb][0] + bs.x, 0.f);
            pk[1] = (__bf16)fmaxf(acc[ca][nb][1] + bs.y, 0.f);
            pk[2] = (__bf16)fmaxf(acc[ca][nb][2] + bs.z, 0.f);
            pk[3] = (__bf16)fmaxf(acc[ca][nb][3] + bs.w, 0.f);
            *(bf16x4*)(Db + swz(r, c0 * 2)) = pk;
        }
    }
}

// Prep: fp32 -> bf16 weights. W0 padded K:3->32 with zeros.
__global__ void prep_kernel(const float* __restrict__ W0,
                            const float* __restrict__ W1,
                            const float* __restrict__ W2,
                            unsigned int* __restrict__ W1b,
                            unsigned int* __restrict__ W2b,
                            unsigned int* __restrict__ W0p) {
    int i = blockIdx.x * 256 + threadIdx.x;  // 0..65535
    float2 v = *(const float2*)(W1 + 2 * i);
    W1b[i] = f2bf(v.x) | (f2bf(v.y) << 16);
    float2 u = *(const float2*)(W2 + 2 * i);
    W2b[i] = f2bf(u.x) | (f2bf(u.y) << 16);
    if (i < NE * HD * 16) {
        int row = i >> 4;
        int kk = (i & 15) * 2;
        float a = (kk < 3) ? W0[row * 3 + kk] : 0.f;
        float b = (kk + 1 < 3) ? W0[row * 3 + kk + 1] : 0.f;
        W0p[i] = f2bf(a) | (f2bf(b) << 16);
    }
}

#define XPS 40   // Xp row stride in shorts (80 B): (5r+lg) mod 8 bijective per 8 lanes -> conflict-free

__global__ __launch_bounds__(256, 4) void moe_main(
    const float* __restrict__ coords,
    const float* __restrict__ b0, const float* __restrict__ b1,
    const float* __restrict__ b2,
    const float* __restrict__ Wo, const float* __restrict__ bo,
    const unsigned short* __restrict__ W0p,
    const unsigned short* __restrict__ W1b,
    const unsigned short* __restrict__ W2b,
    float* __restrict__ out) {
    __shared__ __align__(16) unsigned short hA[TM * HD];   // 16 KB, swizzled 256B rows
    __shared__ __align__(16) unsigned short hB[TM * HD];   // 16 KB
    __shared__ __align__(16) unsigned short Xp[TM * XPS];  // 5 KB, 80B rows
    __shared__ __align__(16) float part[NE * TM];          // 2 KB, per-expert dot accumulators

    const int tid = threadIdx.x;
    const int lane = tid & 63;
    const int w = tid >> 6;
    const int lr = lane & 15;
    const int lg = lane >> 4;
    const int tc = w * 32;
    const int row0 = blockIdx.x * TM;

    // ---- one-pass init: each of 64 threads owns one Xp row; others zero part ----
    if (tid < TM) {
        unsigned int* rowp = (unsigned int*)(Xp + tid * XPS);
        float c0 = coords[(row0 + tid) * 3 + 0];
        float c1 = coords[(row0 + tid) * 3 + 1];
        float c2 = coords[(row0 + tid) * 3 + 2];
        rowp[0] = f2bf(c0) | (f2bf(c1) << 16);
        rowp[1] = f2bf(c2);
#pragma unroll
        for (int i = 2; i < XPS / 2; ++i) rowp[i] = 0;
    } else if (tid >= 128) {
        ((float4*)part)[tid - 128] = (float4){0.f, 0.f, 0.f, 0.f};  // 128 thr x 16B = 2 KB
    }
    bar_lds();

    bf16x8 a0[2][1], a1[2][4], a2[2][4];
    loadA32(W0p, a0, tc, lr, lg);
    loadA128<0, 2>(W1b, a1, tc, lr, lg);

    for (int e = 0; e < NE; ++e) {
        const unsigned short* W1e = W1b + e * HD * HD;
        const unsigned short* W2e = W2b + e * HD * HD;
        const int e1 = (e < NE - 1) ? e + 1 : e;
        f32x4 acc[2][4];

        // ---- layer 0: h1 = relu(X*W0^T + b0) -> hA ----
#pragma unroll
        for (int ca = 0; ca < 2; ++ca)
#pragma unroll
            for (int nb = 0; nb < 4; ++nb) acc[ca][nb] = (f32x4){0.f, 0.f, 0.f, 0.f};
        gemm_core<1, false, XPS * 2>(a0, (const char*)Xp, acc, lr, lg);
        loadA128<2, 4>(W1e, a1, tc, lr, lg);   // in flight across epi + bar
        epi_store(acc, (char*)hA, b0 + e * HD, tc, lr, lg);
        bar_lds();

        // ---- layer 1: h2 = relu(h1*W1^T + b1) -> hB ----
#pragma unroll
        for (int ca = 0; ca < 2; ++ca)
#pragma unroll
            for (int nb = 0; nb < 4; ++nb) acc[ca][nb] = (f32x4){0.f, 0.f, 0.f, 0.f};
        gemm_core<4, true, 0>(a1, (const char*)hA, acc, lr, lg);
        loadA128<0, 2>(W2e, a2, tc, lr, lg);   // in flight across epi + bar
        epi_store(acc, (char*)hB, b1 + e * HD, tc, lr, lg);
        bar_lds();

        // ---- layer 2 + fused output dot ----
        loadA128<2, 4>(W2e, a2, tc, lr, lg);
#pragma unroll
        for (int ca = 0; ca < 2; ++ca)
#pragma unroll
            for (int nb = 0; nb < 4; ++nb) acc[ca][nb] = (f32x4){0.f, 0.f, 0.f, 0.f};
        gemm_core<4, true, 0>(a2, (const char*)hB, acc, lr, lg);
        loadA32(W0p + e1 * HD * 32, a0, tc, lr, lg);      // next-expert prefetch
        loadA128<0, 2>(W1b + e1 * HD * HD, a1, tc, lr, lg);

        {
            const float* b2e = b2 + e * HD;
            const float* Woe = Wo + e * HD;
            float s[4] = {0.f, 0.f, 0.f, 0.f};
#pragma unroll
            for (int ca = 0; ca < 2; ++ca) {
                int c0 = tc + ca * 16 + lg * 4;
                float4 bs = *(const float4*)(b2e + c0);
                float4 wo = *(const float4*)(Woe + c0);
#pragma unroll
                for (int nb = 0; nb < 4; ++nb) {
                    float v0 = fmaxf(acc[ca][nb][0] + bs.x, 0.f);
                    float v1 = fmaxf(acc[ca][nb][1] + bs.y, 0.f);
                    float v2 = fmaxf(acc[ca][nb][2] + bs.z, 0.f);
                    float v3 = fmaxf(acc[ca][nb][3] + bs.w, 0.f);
                    s[nb] += v0 * wo.x + v1 * wo.y + v2 * wo.z + v3 * wo.w;
                }
            }
#pragma unroll
            for (int nb = 0; nb < 4; ++nb) {
                s[nb] += __shfl_xor(s[nb], 16);
                s[nb] += __shfl_xor(s[nb], 32);
            }
            if (lg == 0) {
#pragma unroll
                for (int nb = 0; nb < 4; ++nb)
                    atomicAdd(&part[e * TM + nb * 16 + lr], s[nb]);  // ds_add_f32, no barrier
            }
        }
        // no barrier: hA rewrite (next L0) is safe post-bar2; hB rewrite waits at next bar1
    }

    bar_lds();
    if (tid < TM) {
        float m = -3.0e38f;
#pragma unroll
        for (int e = 0; e < NE; ++e) m = fmaxf(m, part[e * TM + tid] + bo[e]);
        out[row0 + tid] = m;
    }
}

extern "C" void kernel_launch(void* const* d_in, const int* in_sizes, int n_in,
                              void* d_out, int out_size, void* d_ws, size_t ws_size,
                              hipStream_t stream) {
    const float* coords = (const float*)d_in[0];
    const float* W0 = (const float*)d_in[1];
    const float* b0 = (const float*)d_in[2];
    const float* W1 = (const float*)d_in[3];
    const float* b1 = (const float*)d_in[4];
    const float* W2 = (const float*)d_in[5];
    const float* b2 = (const float*)d_in[6];
    const float* Wo = (const float*)d_in[7];
    const float* bo = (const float*)d_in[8];
    float* out = (float*)d_out;

    char* ws = (char*)d_ws;
    unsigned short* W1b = (unsigned short*)(ws);            // 256 KB
    unsigned short* W2b = (unsigned short*)(ws + 262144);   // 256 KB
    unsigned short* W0p = (unsigned short*)(ws + 524288);   // 64 KB

    prep_kernel<<<dim3(256), dim3(256), 0, stream>>>(
        W0, W1, W2, (unsigned int*)W1b, (unsigned int*)W2b, (unsigned int*)W0p);

    moe_main<<<dim3(NPTS / TM), dim3(256), 0, stream>>>(
        coords, b0, b1, b2, Wo, bo, W0p, W1b, W2b, out);
}